// Round 9
// baseline (30.757 us; speedup 1.0000x reference)
//
#include <hip/hip_runtime.h>

#define B_ 32
#define X_ 128
#define Y_ 256
#define C_ 64
#define BDIM 256
#define NPART 4
#define ITEMS_PER_PART (B_ * X_ / NPART)   /* 1024 */
#define MIN_VALF -4294967295.0f

// Insert v into descending sorted triple (m1 >= m2 >= m3), keeping top-3.
__device__ __forceinline__ void insert3(float& m1, float& m2, float& m3, float v) {
    float hi1 = fmaxf(m1, v);
    float lo1 = fminf(m1, v);
    m1 = hi1;
    float hi2 = fmaxf(m2, lo1);
    float lo2 = fminf(m2, lo1);
    m2 = hi2;
    m3 = fmaxf(m3, lo2);
}

// Persistent blocks + 4-way partitioned atomic work queue. Each item is one
// (b,x): 4 waves each own a 64-row y-chunk, one 16-load burst per wave
// (R4/R7 body — the proven best). Stealing keeps R4's single-item dynamic
// balance but removes block redispatch cost; queue-startup (xmask+ymask
// fused trip) of one item overlaps other items' data drains.
__global__ __launch_bounds__(BDIM) void topk_pool_kernel(
    const float* __restrict__ inp,
    const float* __restrict__ xmask,
    const float* __restrict__ ymask,
    float* __restrict__ out,
    unsigned* __restrict__ queues)
{
    const int tid  = threadIdx.x;
    const int lane = tid & 63;
    const int wv   = tid >> 6;                      // wave id = y-chunk, 0..3
    const int c0   = (lane & 15) << 2;              // channel base (float4)
    const int yofs = lane >> 4;                     // y-subgroup 0..3

    const int part   = blockIdx.x & (NPART - 1);
    unsigned* q      = queues + part * 64;          // 256 B apart: no line sharing
    const int gbase  = part * ITEMS_PER_PART;

    __shared__ float lds[4 * 16 * 16];
    __shared__ int   g_sh;

    for (;;) {
        // Loop-top barrier: (a) separates prev item's LDS finalize-reads from
        // next item's LDS writes, (b) orders g_sh rewrite.
        __syncthreads();
        if (tid == 0) g_sh = (int)atomicAdd(q, 1u);
        __syncthreads();
        const int idx = g_sh;
        if (idx >= ITEMS_PER_PART) return;          // uniform exit

        const int w = ((gbase + idx) * 1997) & (B_ * X_ - 1);  // bijective scatter
        const int b = w >> 7;
        const int x = w & (X_ - 1);

        // ---- trip 1: xmask + ymask issued together ----
        const float xm  = xmask[b * X_ + x];
        const float* ym = ymask + b * Y_;
        const float y0v = ym[lane];
        const float y1v = ym[lane + 64];
        const float y2v = ym[lane + 128];
        const float y3v = ym[lane + 192];

        float* orow = out + (size_t)w * (3 * C_);

        if (xm == 0.0f) {                           // block-uniform branch
            if (wv == 0) {
                orow[lane]       = 0.0f;
                orow[64 + lane]  = 0.0f;
                orow[128 + lane] = 0.0f;
            }
            continue;
        }

        float ysum = y0v + y1v + y2v + y3v;
        #pragma unroll
        for (int off = 32; off > 0; off >>= 1) ysum += __shfl_xor(ysum, off);
        const int   ylen    = (int)(ysum + 0.5f);
        const float inv_len = 1.0f / ysum;          // ylen >= 4 per setup

        float m1[4], m2[4], m3[4], s[4];
        #pragma unroll
        for (int j = 0; j < 4; ++j) {
            m1[j] = MIN_VALF; m2[j] = MIN_VALF; m3[j] = MIN_VALF; s[j] = 0.0f;
        }

        const float* base = inp + ((size_t)w << 14) + c0;   // w * Y_*C_
        const int y_lo = wv * 64;
        const int y0   = y_lo + yofs;

        if (y_lo < ylen) {
            if (y_lo + 64 <= ylen) {
                // Full chunk: 16 independent loads in one burst.
                float4 v[16];
                #pragma unroll
                for (int i = 0; i < 16; ++i)
                    v[i] = *reinterpret_cast<const float4*>(base + (size_t)(y0 + 4 * i) * C_);
                #pragma unroll
                for (int i = 0; i < 16; ++i) {
                    float vv[4] = {v[i].x, v[i].y, v[i].z, v[i].w};
                    #pragma unroll
                    for (int j = 0; j < 4; ++j) {
                        s[j] += vv[j];
                        insert3(m1[j], m2[j], m3[j], vv[j]);
                    }
                }
            } else {
                // Partial chunk: clamped rows (always valid), masked consume.
                float4 v[16];
                #pragma unroll
                for (int i = 0; i < 16; ++i) {
                    const int yr = y0 + 4 * i;
                    const int yc = (yr < ylen) ? yr : (ylen - 1);
                    v[i] = *reinterpret_cast<const float4*>(base + (size_t)yc * C_);
                }
                #pragma unroll
                for (int i = 0; i < 16; ++i) {
                    const bool live = (y0 + 4 * i) < ylen;
                    float vv[4] = {v[i].x, v[i].y, v[i].z, v[i].w};
                    #pragma unroll
                    for (int j = 0; j < 4; ++j) {
                        s[j] += live ? vv[j] : 0.0f;
                        insert3(m1[j], m2[j], m3[j], live ? vv[j] : MIN_VALF);
                    }
                }
            }
        }
        // (Waves with y_lo >= ylen keep init values — merge-neutral.)

        // In-wave merge of the 4 y-subgroups.
        #pragma unroll
        for (int step = 0; step < 2; ++step) {
            const int msk = 16 << step;
            #pragma unroll
            for (int j = 0; j < 4; ++j) {
                float o1 = __shfl_xor(m1[j], msk);
                float o2 = __shfl_xor(m2[j], msk);
                float o3 = __shfl_xor(m3[j], msk);
                float os = __shfl_xor(s[j],  msk);
                s[j] += os;
                insert3(m1[j], m2[j], m3[j], o1);
                insert3(m1[j], m2[j], m3[j], o2);
                insert3(m1[j], m2[j], m3[j], o3);
            }
        }

        // Stage per-wave partials.
        if (yofs == 0) {
            float* dst = &lds[(wv * 16 + (lane & 15)) * 16];
            *reinterpret_cast<float4*>(dst +  0) = make_float4(m1[0], m1[1], m1[2], m1[3]);
            *reinterpret_cast<float4*>(dst +  4) = make_float4(m2[0], m2[1], m2[2], m2[3]);
            *reinterpret_cast<float4*>(dst +  8) = make_float4(m3[0], m3[1], m3[2], m3[3]);
            *reinterpret_cast<float4*>(dst + 12) = make_float4(s[0],  s[1],  s[2],  s[3]);
        }
        __syncthreads();

        // Wave 0 merges the 4 chunk-partials; lane == channel.
        if (wv == 0) {
            const int lg = lane >> 2, e = lane & 3;
            float M1 = MIN_VALF, M2 = MIN_VALF, M3 = MIN_VALF, S = 0.0f;
            #pragma unroll
            for (int qq = 0; qq < 4; ++qq) {
                const float* src = &lds[(qq * 16 + lg) * 16];
                float a = src[e], bb = src[4 + e], c = src[8 + e], d = src[12 + e];
                S += d;
                insert3(M1, M2, M3, a);
                insert3(M1, M2, M3, bb);
                insert3(M1, M2, M3, c);
            }
            const float mean = S * inv_len;
            orow[lane]       = M1 * xm;
            orow[64 + lane]  = ((ylen >= 3) ? (M1 + M2 + M3) * (1.0f / 3.0f) : mean) * xm;
            orow[128 + lane] = mean;     // mean_pool is NOT x-masked in ref
        }
        // Next loop-top __syncthreads protects lds before rewrite.
    }
}

extern "C" void kernel_launch(void* const* d_in, const int* in_sizes, int n_in,
                              void* d_out, int out_size, void* d_ws, size_t ws_size,
                              hipStream_t stream) {
    const float* inp   = (const float*)d_in[0];
    const float* xmask = (const float*)d_in[1];
    const float* ymask = (const float*)d_in[2];
    float* out = (float*)d_out;
    unsigned* queues = (unsigned*)d_ws;

    // Zero the 4 queue counters (256 B apart) every launch — deterministic.
    hipMemsetAsync(d_ws, 0, NPART * 64 * sizeof(unsigned), stream);

    const int grid = 1024;   // persistent blocks; co-residency not required
    topk_pool_kernel<<<grid, BDIM, 0, stream>>>(inp, xmask, ymask, out, queues);
}

// Round 10
// 20.182 us; speedup vs baseline: 1.5240x; 1.5240x over previous
//
#include <hip/hip_runtime.h>

#define B_ 32
#define X_ 128
#define Y_ 256
#define C_ 64
#define BDIM 256
#define MIN_VALF -4294967295.0f

// Insert v into descending sorted triple (m1 >= m2 >= m3), keeping top-3.
__device__ __forceinline__ void insert3(float& m1, float& m2, float& m3, float v) {
    float hi1 = fmaxf(m1, v);
    float lo1 = fminf(m1, v);
    m1 = hi1;
    float hi2 = fmaxf(m2, lo1);
    float lo2 = fminf(m2, lo1);
    m2 = hi2;
    m3 = fmaxf(m3, lo2);
}

// FINAL (measured best, 20.33 us = practical roofline):
// one block per (b,x), 4 waves each owning a 64-row y-chunk; 4-deep ILP
// load loop; shfl merge of the 4 y-subgroups; LDS merge of the 4 waves.
// Floor = 68.8 MB live fetch @ ~6.3 TB/s (10.9 us) + ramp/tail + fixed
// graph-replay overhead. Static multi-item / work-stealing / deeper ILP
// all measured neutral-to-worse (R5-R9).
__global__ __launch_bounds__(BDIM) void topk_pool_kernel(
    const float* __restrict__ inp,
    const float* __restrict__ xmask,
    const float* __restrict__ ymask,
    float* __restrict__ out)
{
    const int tid  = threadIdx.x;
    const int lane = tid & 63;
    const int wv   = tid >> 6;                      // wave id = y-chunk, 0..3

    // Bijective scatter of block -> (b,x) to mix long/short blocks across CUs.
    const int w = (blockIdx.x * 1997) & (B_ * X_ - 1);
    const int b = w >> 7;
    const int x = w & (X_ - 1);

    __shared__ float lds[4 * 16 * 16];              // [wave][chgrp][16 floats]

    // ylen = sum(y_mask[b,:]) — prefix mask.
    const float* ym = ymask + b * Y_;
    float ysum = ym[lane] + ym[lane + 64] + ym[lane + 128] + ym[lane + 192];
    #pragma unroll
    for (int off = 32; off > 0; off >>= 1) ysum += __shfl_xor(ysum, off);
    const int   ylen    = (int)(ysum + 0.5f);
    const float inv_len = 1.0f / fmaxf(ysum, 1.0f);

    const float xm = xmask[b * X_ + x];
    float* orow = out + (size_t)w * (3 * C_);

    if (xm == 0.0f) {                               // uniform across block
        if (wv == 0) {
            orow[lane]       = 0.0f;
            orow[64 + lane]  = 0.0f;
            orow[128 + lane] = 0.0f;
        }
        return;                                     // ALL waves return: no sync hazard
    }

    const int c0   = (lane & 15) << 2;              // channel base (float4)
    const int yofs = lane >> 4;                     // y-subgroup 0..3

    float m1[4], m2[4], m3[4], s[4];
    #pragma unroll
    for (int j = 0; j < 4; ++j) {
        m1[j] = MIN_VALF; m2[j] = MIN_VALF; m3[j] = MIN_VALF; s[j] = 0.0f;
    }

    const float* base = inp + (size_t)(b * X_ + x) * (Y_ * C_) + c0;
    const int y_lo = wv * 64;
    const int y_hi = (y_lo + 64 < ylen) ? (y_lo + 64) : ylen;

    int y = y_lo + yofs;
    // Full pass: rows y, y+4, y+8, y+12 (4 loads in flight).
    for (; y + 12 < y_hi; y += 16) {
        float4 v0 = *reinterpret_cast<const float4*>(base + (size_t)(y     ) * C_);
        float4 v1 = *reinterpret_cast<const float4*>(base + (size_t)(y +  4) * C_);
        float4 v2 = *reinterpret_cast<const float4*>(base + (size_t)(y +  8) * C_);
        float4 v3 = *reinterpret_cast<const float4*>(base + (size_t)(y + 12) * C_);
        float a0[4] = {v0.x, v0.y, v0.z, v0.w};
        float a1[4] = {v1.x, v1.y, v1.z, v1.w};
        float a2[4] = {v2.x, v2.y, v2.z, v2.w};
        float a3[4] = {v3.x, v3.y, v3.z, v3.w};
        #pragma unroll
        for (int j = 0; j < 4; ++j) {
            s[j] += a0[j]; insert3(m1[j], m2[j], m3[j], a0[j]);
            s[j] += a1[j]; insert3(m1[j], m2[j], m3[j], a1[j]);
            s[j] += a2[j]; insert3(m1[j], m2[j], m3[j], a2[j]);
            s[j] += a3[j]; insert3(m1[j], m2[j], m3[j], a3[j]);
        }
    }
    // Remainder (<=3 rows for this subgroup).
    for (; y < y_hi; y += 4) {
        float4 v = *reinterpret_cast<const float4*>(base + (size_t)y * C_);
        float vv[4] = {v.x, v.y, v.z, v.w};
        #pragma unroll
        for (int j = 0; j < 4; ++j) {
            s[j] += vv[j]; insert3(m1[j], m2[j], m3[j], vv[j]);
        }
    }

    // In-wave merge of the 4 y-subgroups (after this every lane holds the
    // wave-chunk result for its 4 channels).
    #pragma unroll
    for (int step = 0; step < 2; ++step) {
        const int msk = 16 << step;
        #pragma unroll
        for (int j = 0; j < 4; ++j) {
            float o1 = __shfl_xor(m1[j], msk);
            float o2 = __shfl_xor(m2[j], msk);
            float o3 = __shfl_xor(m3[j], msk);
            float os = __shfl_xor(s[j],  msk);
            s[j] += os;
            insert3(m1[j], m2[j], m3[j], o1);
            insert3(m1[j], m2[j], m3[j], o2);
            insert3(m1[j], m2[j], m3[j], o3);
        }
    }

    // Stage per-wave partials: lds[wv][chgrp][m1[0..3] m2[0..3] m3[0..3] s[0..3]]
    if (yofs == 0) {
        float* dst = &lds[(wv * 16 + (lane & 15)) * 16];
        *reinterpret_cast<float4*>(dst +  0) = make_float4(m1[0], m1[1], m1[2], m1[3]);
        *reinterpret_cast<float4*>(dst +  4) = make_float4(m2[0], m2[1], m2[2], m2[3]);
        *reinterpret_cast<float4*>(dst +  8) = make_float4(m3[0], m3[1], m3[2], m3[3]);
        *reinterpret_cast<float4*>(dst + 12) = make_float4(s[0],  s[1],  s[2],  s[3]);
    }
    __syncthreads();

    // Wave 0 merges the 4 chunk-partials; lane == channel.
    if (wv == 0) {
        const int ch = lane, lg = ch >> 2, e = ch & 3;
        float M1 = MIN_VALF, M2 = MIN_VALF, M3 = MIN_VALF, S = 0.0f;
        #pragma unroll
        for (int q = 0; q < 4; ++q) {
            const float* src = &lds[(q * 16 + lg) * 16];
            float a = src[e], bb = src[4 + e], c = src[8 + e], d = src[12 + e];
            S += d;
            insert3(M1, M2, M3, a);
            insert3(M1, M2, M3, bb);
            insert3(M1, M2, M3, c);
        }
        const float mean = S * inv_len;
        const float top1 = ((ylen >= 1) ? M1 : mean) * xm;
        const float top3 = ((ylen >= 3) ? (M1 + M2 + M3) * (1.0f / 3.0f) : mean) * xm;
        orow[ch]       = top1;
        orow[64 + ch]  = top3;
        orow[128 + ch] = mean;          // mean_pool is NOT x-masked in ref
    }
}

extern "C" void kernel_launch(void* const* d_in, const int* in_sizes, int n_in,
                              void* d_out, int out_size, void* d_ws, size_t ws_size,
                              hipStream_t stream) {
    const float* inp   = (const float*)d_in[0];
    const float* xmask = (const float*)d_in[1];
    const float* ymask = (const float*)d_in[2];
    float* out = (float*)d_out;

    const int grid = B_ * X_;           // one block per (b,x)
    topk_pool_kernel<<<grid, BDIM, 0, stream>>>(inp, xmask, ymask, out);
}